// Round 2
// baseline (2733.283 us; speedup 1.0000x reference)
//
#include <hip/hip_runtime.h>
#include <math.h>

#define B_N 2048
#define D_N 1024
#define H_N 32768
#define K_SEL 256
#define M_CAND 288
#define EPS_V 1e-5f

__device__ __forceinline__ unsigned orderf(float x) {
    unsigned f = __float_as_uint(x);
    return (f & 0x80000000u) ? ~f : (f | 0x80000000u);
}

// ---------------- LayerNorm-style preprocess (fp32, for GEMM + decode denorm) ----------------
__global__ __launch_bounds__(256) void ln_kernel(const float* __restrict__ x,
        float* __restrict__ xn, float* __restrict__ mu_out, float* __restrict__ std_out) {
    int b = blockIdx.x, t = threadIdx.x;
    const float4* row = (const float4*)(x + (size_t)b * D_N);
    float4 v = row[t];
    float s  = v.x + v.y + v.z + v.w;
    float ss = v.x*v.x + v.y*v.y + v.z*v.z + v.w*v.w;
    #pragma unroll
    for (int off = 32; off > 0; off >>= 1) {
        s  += __shfl_down(s, off);
        ss += __shfl_down(ss, off);
    }
    __shared__ float ls[4], lss[4];
    __shared__ float smu, sinv;
    int w = t >> 6;
    if ((t & 63) == 0) { ls[w] = s; lss[w] = ss; }
    __syncthreads();
    if (t == 0) {
        float S  = ls[0] + ls[1] + ls[2] + ls[3];
        float SS = lss[0] + lss[1] + lss[2] + lss[3];
        float mu = S / (float)D_N;
        float var = (SS - S * S / (float)D_N) / (float)(D_N - 1);
        float sd = sqrtf(fmaxf(var, 0.f));
        smu = mu; sinv = 1.f / (sd + EPS_V);
        mu_out[b] = mu; std_out[b] = sd;
    }
    __syncthreads();
    float mu = smu, inv = sinv;
    float4 o;
    o.x = (v.x - mu) * inv; o.y = (v.y - mu) * inv;
    o.z = (v.z - mu) * inv; o.w = (v.w - mu) * inv;
    ((float4*)(xn + (size_t)b * D_N))[t] = o;
}

// ---------------- encoder row inverse norms (f64 accurate) ----------------
__global__ __launch_bounds__(256) void wnorm_kernel(const float* __restrict__ W,
        float* __restrict__ inv_norm, double* __restrict__ inv_norm_d) {
    int h = blockIdx.x, t = threadIdx.x;
    const float4* row = (const float4*)(W + (size_t)h * D_N);
    float4 v = row[t];
    double ss = (double)v.x*v.x + (double)v.y*v.y + (double)v.z*v.z + (double)v.w*v.w;
    #pragma unroll
    for (int off = 32; off > 0; off >>= 1) ss += __shfl_down(ss, off);
    __shared__ double lss[4];
    int w = t >> 6;
    if ((t & 63) == 0) lss[w] = ss;
    __syncthreads();
    if (t == 0) {
        double SS = lss[0] + lss[1] + lss[2] + lss[3];
        double n = sqrt(SS);
        if (n < 1e-12) n = 1e-12;
        inv_norm_d[h] = 1.0 / n;
        inv_norm[h] = (float)(1.0 / n);
    }
}

// ---------------- fp32 encoder GEMM: C[b,h] = dot(xn[b,:], W[h,:]) * inv_norm[h] ----------------
#define BM 128
#define BN 128
#define BK 16

__global__ __launch_bounds__(256) void enc_gemm(const float* __restrict__ A,
        const float* __restrict__ Wt, const float* __restrict__ invn,
        float* __restrict__ C) {
    __shared__ float As[BK][BM + 4];
    __shared__ float Bs[BK][BN + 4];
    int tid = threadIdx.x;
    int bx = blockIdx.x;   // H tile
    int by = blockIdx.y;   // B tile
    const int tx = tid & 15, ty = tid >> 4;
    float acc[8][8] = {};

    int sr = tid >> 2;               // 0..63
    int sc = (tid & 3) * 4;          // 0,4,8,12
    const float* Aptr = A  + ((size_t)(by * BM + sr)) * D_N + sc;
    const float* Bptr = Wt + ((size_t)(bx * BN + sr)) * D_N + sc;

    for (int k0 = 0; k0 < D_N; k0 += BK) {
        float4 a0 = *(const float4*)(Aptr + k0);
        float4 a1 = *(const float4*)(Aptr + (size_t)64 * D_N + k0);
        float4 b0 = *(const float4*)(Bptr + k0);
        float4 b1 = *(const float4*)(Bptr + (size_t)64 * D_N + k0);
        __syncthreads();   // protect previous iteration's reads
        As[sc + 0][sr] = a0.x; As[sc + 1][sr] = a0.y; As[sc + 2][sr] = a0.z; As[sc + 3][sr] = a0.w;
        As[sc + 0][sr + 64] = a1.x; As[sc + 1][sr + 64] = a1.y; As[sc + 2][sr + 64] = a1.z; As[sc + 3][sr + 64] = a1.w;
        Bs[sc + 0][sr] = b0.x; Bs[sc + 1][sr] = b0.y; Bs[sc + 2][sr] = b0.z; Bs[sc + 3][sr] = b0.w;
        Bs[sc + 0][sr + 64] = b1.x; Bs[sc + 1][sr + 64] = b1.y; Bs[sc + 2][sr + 64] = b1.z; Bs[sc + 3][sr + 64] = b1.w;
        __syncthreads();
        #pragma unroll
        for (int kk = 0; kk < BK; kk++) {
            float av[8], bv[8];
            *(float4*)&av[0] = *(const float4*)&As[kk][ty * 4];
            *(float4*)&av[4] = *(const float4*)&As[kk][64 + ty * 4];
            *(float4*)&bv[0] = *(const float4*)&Bs[kk][tx * 4];
            *(float4*)&bv[4] = *(const float4*)&Bs[kk][64 + tx * 4];
            #pragma unroll
            for (int i = 0; i < 8; i++)
                #pragma unroll
                for (int j = 0; j < 8; j++)
                    acc[i][j] += av[i] * bv[j];
        }
    }

    int rbase = by * BM + ty * 4;
    int cbase = bx * BN + tx * 4;
    float inv0[4], inv1[4];
    #pragma unroll
    for (int j = 0; j < 4; j++) { inv0[j] = invn[cbase + j]; inv1[j] = invn[cbase + 64 + j]; }
    #pragma unroll
    for (int ih = 0; ih < 2; ih++) {
        #pragma unroll
        for (int i = 0; i < 4; i++) {
            int r = rbase + ih * 64 + i;
            float* crow = C + (size_t)r * H_N;
            int ai = ih * 4 + i;
            float4 v0, v1;
            v0.x = acc[ai][0] * inv0[0]; v0.y = acc[ai][1] * inv0[1];
            v0.z = acc[ai][2] * inv0[2]; v0.w = acc[ai][3] * inv0[3];
            v1.x = acc[ai][4] * inv1[0]; v1.y = acc[ai][5] * inv1[1];
            v1.z = acc[ai][6] * inv1[2]; v1.w = acc[ai][7] * inv1[3];
            *(float4*)(crow + cbase) = v0;
            *(float4*)(crow + cbase + 64) = v1;
        }
    }
}

// ---------------- W_dec transpose [D][H] -> [H][D] ----------------
__global__ void transpose_kernel(const float* __restrict__ in, float* __restrict__ out) {
    __shared__ float tile[32][33];
    int x  = blockIdx.x * 32 + threadIdx.x;     // h
    int y0 = blockIdx.y * 32;                   // d
    #pragma unroll
    for (int j = threadIdx.y; j < 32; j += 8)
        tile[j][threadIdx.x] = in[(size_t)(y0 + j) * H_N + x];
    __syncthreads();
    int xo  = blockIdx.y * 32 + threadIdx.x;    // d
    int yo0 = blockIdx.x * 32;                  // h
    #pragma unroll
    for (int j = threadIdx.y; j < 32; j += 8)
        out[(size_t)(yo0 + j) * D_N + xo] = tile[threadIdx.x][j];
}

// ---------------- per-row top-M candidate extraction (exact fp32 semantics) ----------------
__global__ __launch_bounds__(1024) void candk_kernel(const float* __restrict__ lat,
        int* __restrict__ cand_idx) {
    int b = blockIdx.x, t = threadIdx.x;
    const float* row = lat + (size_t)b * H_N;
    __shared__ unsigned hist[2048];
    __shared__ unsigned scan[1024];
    __shared__ int sh_bin1, sh_above1, sh_bin2, sh_aboveT;
    __shared__ unsigned cand_u[512];
    __shared__ int cand_i[512];
    __shared__ int ncand;
    __shared__ unsigned sh_uthr;
    __shared__ int sh_eqlim, sh_pos;

    hist[t] = 0; hist[t + 1024] = 0;
    if (t == 0) { ncand = 0; sh_pos = 0; }
    __syncthreads();
    for (int i = t; i < H_N; i += 1024) {
        unsigned u = orderf(row[i]);
        atomicAdd(&hist[u >> 21], 1u);
    }
    __syncthreads();
    unsigned s2 = hist[2 * t] + hist[2 * t + 1];
    scan[t] = s2;
    __syncthreads();
    for (int off = 1; off < 1024; off <<= 1) {
        unsigned v = (t + off < 1024) ? scan[t + off] : 0u;
        __syncthreads();
        scan[t] += v;
        __syncthreads();
    }
    unsigned c0 = scan[t];                       // csum(2t)
    unsigned c1 = c0 - hist[2 * t];              // csum(2t+1)
    unsigned c2 = (t < 1023) ? scan[t + 1] : 0u; // csum(2t+2)
    if (c0 >= (unsigned)M_CAND && c1 < (unsigned)M_CAND) { sh_bin1 = 2 * t;     sh_above1 = (int)c1; }
    if (c1 >= (unsigned)M_CAND && c2 < (unsigned)M_CAND) { sh_bin1 = 2 * t + 1; sh_above1 = (int)c2; }
    __syncthreads();
    int bin1 = sh_bin1, above1 = sh_above1;
    if (t < 256) hist[t] = 0;
    __syncthreads();
    for (int i = t; i < H_N; i += 1024) {
        unsigned u = orderf(row[i]);
        if ((int)(u >> 21) == bin1) atomicAdd(&hist[(u >> 13) & 0xFFu], 1u);
    }
    __syncthreads();
    if (t == 0) {
        int need = M_CAND - above1;
        unsigned acc = 0; int bin2 = 0, above2 = 0;
        for (int j = 255; j >= 0; j--) {
            unsigned nacc = acc + hist[j];
            if (acc < (unsigned)need && nacc >= (unsigned)need) { bin2 = j; above2 = (int)acc; break; }
            acc = nacc;
        }
        sh_bin2 = bin2; sh_aboveT = above1 + above2;
    }
    __syncthreads();
    unsigned pref = ((unsigned)bin1 << 8) | (unsigned)sh_bin2;
    int aboveT = sh_aboveT;
    for (int i = t; i < H_N; i += 1024) {
        unsigned u = orderf(row[i]);
        if ((u >> 13) == pref) {
            int p = atomicAdd(&ncand, 1);
            if (p < 512) { cand_u[p] = u; cand_i[p] = i; }
        }
    }
    __syncthreads();
    if (t == 0) {
        int c = ncand < 512 ? ncand : 512;
        int need = M_CAND - aboveT;   // 1-based rank within candidates
        unsigned ut = 0; int eqlim = 0x7fffffff;
        for (int i = 0; i < c; i++) {
            unsigned u = cand_u[i];
            int gt = 0, eqc = 0;
            for (int j = 0; j < c; j++) { gt += (cand_u[j] > u); eqc += (cand_u[j] == u); }
            if (gt < need && gt + eqc >= need) {
                ut = u;
                int need_eq = need - gt;
                int lim = -1;
                for (int r = 0; r < need_eq; r++) {
                    int best = 0x7fffffff;
                    for (int j = 0; j < c; j++)
                        if (cand_u[j] == u && cand_i[j] > lim && cand_i[j] < best) best = cand_i[j];
                    lim = best;
                }
                eqlim = lim;
                break;
            }
        }
        sh_uthr = ut; sh_eqlim = eqlim;
    }
    __syncthreads();
    unsigned ut = sh_uthr; int lim = sh_eqlim;
    for (int i = t; i < H_N; i += 1024) {
        unsigned u = orderf(row[i]);
        if (u > ut || (u == ut && i <= lim)) {
            int p = atomicAdd(&sh_pos, 1);
            if (p < M_CAND) cand_idx[(size_t)b * M_CAND + p] = i;
        }
    }
    __syncthreads();
    // safety tail-fill with distinct negative sentinels (should never trigger)
    for (int p = sh_pos + t; p < M_CAND; p += 1024)
        cand_idx[(size_t)b * M_CAND + p] = -(p + 1);
}

// ---------------- f64 refine: recompute candidate latents exactly, pick true top-256 ----------------
__global__ __launch_bounds__(256) void refine_kernel(const float* __restrict__ x,
        const float* __restrict__ Wenc, const double* __restrict__ invn_d,
        const int* __restrict__ cand, int* __restrict__ sel_idx, float* __restrict__ sel_val) {
    int b = blockIdx.x, t = threadIdx.x;
    int lane = t & 63, w = t >> 6;
    __shared__ double xs[D_N];
    __shared__ double vals[M_CAND];
    __shared__ int idxs[M_CAND];
    __shared__ double red[8];
    __shared__ double smu, sinv;

    const float4* row4 = (const float4*)(x + (size_t)b * D_N);
    float4 v = row4[t];
    double s  = (double)v.x + (double)v.y + (double)v.z + (double)v.w;
    double ss = (double)v.x*v.x + (double)v.y*v.y + (double)v.z*v.z + (double)v.w*v.w;
    #pragma unroll
    for (int off = 32; off > 0; off >>= 1) {
        s  += __shfl_down(s, off);
        ss += __shfl_down(ss, off);
    }
    if ((t & 63) == 0) { red[w] = s; red[4 + w] = ss; }
    __syncthreads();
    if (t == 0) {
        double S  = red[0] + red[1] + red[2] + red[3];
        double SS = red[4] + red[5] + red[6] + red[7];
        double mu = S / (double)D_N;
        double var = (SS - S * S / (double)D_N) / (double)(D_N - 1);
        double sd = sqrt(var > 0.0 ? var : 0.0);
        smu = mu; sinv = 1.0 / (sd + 1e-5);
    }
    __syncthreads();
    double mu = smu, inv = sinv;
    xs[4*t + 0] = ((double)v.x - mu) * inv;
    xs[4*t + 1] = ((double)v.y - mu) * inv;
    xs[4*t + 2] = ((double)v.z - mu) * inv;
    xs[4*t + 3] = ((double)v.w - mu) * inv;
    __syncthreads();

    for (int c = w; c < M_CAND; c += 4) {
        int h = cand[(size_t)b * M_CAND + c];
        if ((unsigned)h < (unsigned)H_N) {
            const float* wr = Wenc + (size_t)h * D_N;
            double acc = 0.0;
            for (int d = lane; d < D_N; d += 64) acc += xs[d] * (double)wr[d];
            #pragma unroll
            for (int off = 32; off > 0; off >>= 1) acc += __shfl_down(acc, off);
            if (lane == 0) { vals[c] = acc * invn_d[h]; idxs[c] = h; }
        } else {
            if (lane == 0) { vals[c] = -1e300; idxs[c] = h; }  // distinct negatives
        }
    }
    __syncthreads();
    for (int c = t; c < M_CAND; c += 256) {
        double vv = vals[c]; int id = idxs[c];
        int r = 0;
        for (int j = 0; j < M_CAND; j++) {
            double vj = vals[j];
            r += (vj > vv) || (vj == vv && idxs[j] < id);
        }
        if (r < K_SEL) {
            sel_idx[(size_t)b * K_SEL + r] = id;
            sel_val[(size_t)b * K_SEL + r] = (float)vv;
        }
    }
}

// ---------------- sparse decode + denorm ----------------
__global__ __launch_bounds__(256) void decode_kernel(const int* __restrict__ sel_idx,
        const float* __restrict__ sel_val, const float* __restrict__ Wdt,
        const float* __restrict__ mu, const float* __restrict__ stdv,
        float* __restrict__ out) {
    int b = blockIdx.x, t = threadIdx.x;
    __shared__ int sidx[K_SEL];
    __shared__ float sval[K_SEL];
    sidx[t] = sel_idx[(size_t)b * K_SEL + t];
    sval[t] = sel_val[(size_t)b * K_SEL + t];
    __syncthreads();
    float4 acc = {0.f, 0.f, 0.f, 0.f};
    for (int k = 0; k < K_SEL; k++) {
        int h = sidx[k];
        if ((unsigned)h < (unsigned)H_N) {
            const float4* wrow = (const float4*)(Wdt + (size_t)h * D_N);
            float4 w = wrow[t];
            float v = sval[k];
            acc.x += v * w.x; acc.y += v * w.y; acc.z += v * w.z; acc.w += v * w.w;
        }
    }
    float m = mu[b], sd = stdv[b];
    float4 o;
    o.x = acc.x * sd + m; o.y = acc.y * sd + m;
    o.z = acc.z * sd + m; o.w = acc.w * sd + m;
    ((float4*)(out + (size_t)b * D_N))[t] = o;
}

extern "C" void kernel_launch(void* const* d_in, const int* in_sizes, int n_in,
                              void* d_out, int out_size, void* d_ws, size_t ws_size,
                              hipStream_t stream) {
    const float* txt  = (const float*)d_in[0];
    const float* Wenc = (const float*)d_in[1];
    const float* Wdec = (const float*)d_in[2];
    float* recons = (float*)d_out;
    float* lat    = (float*)d_out + (size_t)B_N * D_N;

    char* p = (char*)d_ws;
    float* xn = (float*)p;        p += (size_t)B_N * D_N * 4;
    float* muv = (float*)p;       p += (size_t)B_N * 4;
    float* stdv = (float*)p;      p += (size_t)B_N * 4;
    float* invn = (float*)p;      p += (size_t)H_N * 4;
    double* invn_d = (double*)p;  p += (size_t)H_N * 8;
    int* candidx = (int*)p;       p += (size_t)B_N * M_CAND * 4;
    int* selidx = (int*)p;        p += (size_t)B_N * K_SEL * 4;
    float* selval = (float*)p;    p += (size_t)B_N * K_SEL * 4;
    float* Wdt = (float*)p;       p += (size_t)H_N * D_N * 4;

    ln_kernel<<<B_N, 256, 0, stream>>>(txt, xn, muv, stdv);
    wnorm_kernel<<<H_N, 256, 0, stream>>>(Wenc, invn, invn_d);
    enc_gemm<<<dim3(H_N / BN, B_N / BM), 256, 0, stream>>>(xn, Wenc, invn, lat);
    transpose_kernel<<<dim3(H_N / 32, D_N / 32), dim3(32, 8), 0, stream>>>(Wdec, Wdt);
    candk_kernel<<<B_N, 1024, 0, stream>>>(lat, candidx);
    refine_kernel<<<B_N, 256, 0, stream>>>(txt, Wenc, invn_d, candidx, selidx, selval);
    decode_kernel<<<B_N, 256, 0, stream>>>(selidx, selval, Wdt, muv, stdv, recons);
}

// Round 3
// 1329.946 us; speedup vs baseline: 2.0552x; 2.0552x over previous
//
#include <hip/hip_runtime.h>
#include <math.h>

#define B_N 2048
#define D_N 1024
#define H_N 32768
#define K_SEL 256
#define M_CAND 320
#define EPS_V 1e-5f

typedef __bf16 bf16x8 __attribute__((ext_vector_type(8)));
typedef float f32x4 __attribute__((ext_vector_type(4)));

__device__ __forceinline__ unsigned orderf(float x) {
    unsigned f = __float_as_uint(x);
    return (f & 0x80000000u) ? ~f : (f | 0x80000000u);
}

__device__ __forceinline__ unsigned short f2bf(float f) {
    unsigned u = __float_as_uint(f);
    unsigned r = u + 0x7FFFu + ((u >> 16) & 1u);   // RNE
    return (unsigned short)(r >> 16);
}

__device__ __forceinline__ float bf2f(unsigned short b) {
    return __uint_as_float((unsigned)b << 16);
}

// ---------------- LN preprocess -> bf16 xn + mu/std ----------------
__global__ __launch_bounds__(256) void ln_kernel(const float* __restrict__ x,
        unsigned short* __restrict__ xnbf, float* __restrict__ mu_out, float* __restrict__ std_out) {
    int b = blockIdx.x, t = threadIdx.x;
    const float4* row = (const float4*)(x + (size_t)b * D_N);
    float4 v = row[t];
    float s  = v.x + v.y + v.z + v.w;
    float ss = v.x*v.x + v.y*v.y + v.z*v.z + v.w*v.w;
    #pragma unroll
    for (int off = 32; off > 0; off >>= 1) {
        s  += __shfl_down(s, off);
        ss += __shfl_down(ss, off);
    }
    __shared__ float ls[4], lss[4];
    __shared__ float smu, sinv;
    int w = t >> 6;
    if ((t & 63) == 0) { ls[w] = s; lss[w] = ss; }
    __syncthreads();
    if (t == 0) {
        float S  = ls[0] + ls[1] + ls[2] + ls[3];
        float SS = lss[0] + lss[1] + lss[2] + lss[3];
        float mu = S / (float)D_N;
        float var = (SS - S * S / (float)D_N) / (float)(D_N - 1);
        float sd = sqrtf(fmaxf(var, 0.f));
        smu = mu; sinv = 1.f / (sd + EPS_V);
        mu_out[b] = mu; std_out[b] = sd;
    }
    __syncthreads();
    float mu = smu, inv = sinv;
    ushort4 o;
    o.x = f2bf((v.x - mu) * inv); o.y = f2bf((v.y - mu) * inv);
    o.z = f2bf((v.z - mu) * inv); o.w = f2bf((v.w - mu) * inv);
    *(ushort4*)(xnbf + (size_t)b * D_N + t * 4) = o;
}

// ---------------- W_enc: f64 row norm, bf16 normalized rows ----------------
__global__ __launch_bounds__(256) void wconv_kernel(const float* __restrict__ W,
        unsigned short* __restrict__ Wbf, double* __restrict__ inv_norm_d) {
    int h = blockIdx.x, t = threadIdx.x;
    const float4* row = (const float4*)(W + (size_t)h * D_N);
    float4 v = row[t];
    double ss = (double)v.x*v.x + (double)v.y*v.y + (double)v.z*v.z + (double)v.w*v.w;
    #pragma unroll
    for (int off = 32; off > 0; off >>= 1) ss += __shfl_down(ss, off);
    __shared__ double lss[4];
    __shared__ float sinv;
    int w = t >> 6;
    if ((t & 63) == 0) lss[w] = ss;
    __syncthreads();
    if (t == 0) {
        double SS = lss[0] + lss[1] + lss[2] + lss[3];
        double n = sqrt(SS);
        if (n < 1e-12) n = 1e-12;
        inv_norm_d[h] = 1.0 / n;
        sinv = (float)(1.0 / n);
    }
    __syncthreads();
    float invf = sinv;
    ushort4 o;
    o.x = f2bf(v.x * invf); o.y = f2bf(v.y * invf);
    o.z = f2bf(v.z * invf); o.w = f2bf(v.w * invf);
    *(ushort4*)(Wbf + (size_t)h * D_N + t * 4) = o;
}

// ---------------- bf16 MFMA GEMM: lat[b,h] = dot(xnbf[b,:], Wbf[h,:]) ----------------
// 128x128 tile, BK=32, 4 waves x (64x64), reg-staged LDS with next-tile prefetch.
__global__ __launch_bounds__(256) void enc_gemm_bf16(const unsigned short* __restrict__ A,
        const unsigned short* __restrict__ Bm, float* __restrict__ C) {
    __shared__ alignas(16) unsigned short As[128 * 32];
    __shared__ alignas(16) unsigned short Bs[128 * 32];
    int t = threadIdx.x;
    int wid = t >> 6, lane = t & 63;
    int bn = blockIdx.x, bm = blockIdx.y;
    int wr = wid >> 1, wc = wid & 1;
    int fr = lane & 15, kq = lane >> 4;

    size_t arow0 = (size_t)bm * 128;
    size_t brow0 = (size_t)bn * 128;

    // staging: chunk e in [0,512), row=e>>2, kslot=e&3; thread t owns e=t and e=256+t
    const unsigned short* gA0 = A  + (arow0 + (t >> 2)) * D_N + (t & 3) * 8;
    const unsigned short* gA1 = A  + (arow0 + 64 + (t >> 2)) * D_N + (t & 3) * 8;
    const unsigned short* gB0 = Bm + (brow0 + (t >> 2)) * D_N + (t & 3) * 8;
    const unsigned short* gB1 = Bm + (brow0 + 64 + (t >> 2)) * D_N + (t & 3) * 8;

    f32x4 acc[4][4];
    #pragma unroll
    for (int i = 0; i < 4; i++)
        #pragma unroll
        for (int j = 0; j < 4; j++)
            acc[i][j] = (f32x4){0.f, 0.f, 0.f, 0.f};

    uint4 ra0 = *(const uint4*)(gA0);
    uint4 ra1 = *(const uint4*)(gA1);
    uint4 rb0 = *(const uint4*)(gB0);
    uint4 rb1 = *(const uint4*)(gB1);

    for (int ks = 0; ks < D_N / 32; ks++) {
        __syncthreads();   // previous compute done reading LDS
        *(uint4*)&As[t * 8]        = ra0;
        *(uint4*)&As[2048 + t * 8] = ra1;
        *(uint4*)&Bs[t * 8]        = rb0;
        *(uint4*)&Bs[2048 + t * 8] = rb1;
        __syncthreads();
        if (ks + 1 < D_N / 32) {   // prefetch next K-tile; latency hides under MFMAs
            int k0 = (ks + 1) * 32;
            ra0 = *(const uint4*)(gA0 + k0);
            ra1 = *(const uint4*)(gA1 + k0);
            rb0 = *(const uint4*)(gB0 + k0);
            rb1 = *(const uint4*)(gB1 + k0);
        }
        bf16x8 af[4], bfr[4];
        #pragma unroll
        for (int i = 0; i < 4; i++) {
            int ra = wr * 64 + i * 16 + fr;
            af[i] = *(const bf16x8*)&As[ra * 32 + kq * 8];
            int rb = wc * 64 + i * 16 + fr;
            bfr[i] = *(const bf16x8*)&Bs[rb * 32 + kq * 8];
        }
        #pragma unroll
        for (int i = 0; i < 4; i++)
            #pragma unroll
            for (int j = 0; j < 4; j++)
                acc[i][j] = __builtin_amdgcn_mfma_f32_16x16x32_bf16(af[i], bfr[j], acc[i][j], 0, 0, 0);
    }

    // epilogue: C/D layout col=lane&15, row=(lane>>4)*4+reg
    #pragma unroll
    for (int i = 0; i < 4; i++) {
        int r0 = bm * 128 + wr * 64 + i * 16 + kq * 4;
        #pragma unroll
        for (int j = 0; j < 4; j++) {
            int c = bn * 128 + wc * 64 + j * 16 + fr;
            #pragma unroll
            for (int r = 0; r < 4; r++)
                C[(size_t)(r0 + r) * H_N + c] = acc[i][j][r];
        }
    }
}

// ---------------- W_dec transpose [D][H] -> bf16 [H][D] ----------------
__global__ void transpose_kernel(const float* __restrict__ in, unsigned short* __restrict__ out) {
    __shared__ float tile[32][33];
    int x  = blockIdx.x * 32 + threadIdx.x;     // h
    int y0 = blockIdx.y * 32;                   // d
    #pragma unroll
    for (int j = threadIdx.y; j < 32; j += 8)
        tile[j][threadIdx.x] = in[(size_t)(y0 + j) * H_N + x];
    __syncthreads();
    int xo  = blockIdx.y * 32 + threadIdx.x;    // d
    int yo0 = blockIdx.x * 32;                  // h
    #pragma unroll
    for (int j = threadIdx.y; j < 32; j += 8)
        out[(size_t)(yo0 + j) * D_N + xo] = f2bf(tile[threadIdx.x][j]);
}

// ---------------- per-row top-M candidate extraction (fp32 latents) ----------------
__global__ __launch_bounds__(1024) void candk_kernel(const float* __restrict__ lat,
        int* __restrict__ cand_idx) {
    int b = blockIdx.x, t = threadIdx.x;
    const float* row = lat + (size_t)b * H_N;
    __shared__ unsigned hist[2048];
    __shared__ unsigned scan[1024];
    __shared__ int sh_bin1, sh_above1, sh_bin2, sh_aboveT;
    __shared__ unsigned cand_u[512];
    __shared__ int cand_i[512];
    __shared__ int ncand;
    __shared__ unsigned sh_uthr;
    __shared__ int sh_eqlim, sh_pos;

    hist[t] = 0; hist[t + 1024] = 0;
    if (t == 0) { ncand = 0; sh_pos = 0; }
    __syncthreads();
    for (int i = t; i < H_N; i += 1024) {
        unsigned u = orderf(row[i]);
        atomicAdd(&hist[u >> 21], 1u);
    }
    __syncthreads();
    unsigned s2 = hist[2 * t] + hist[2 * t + 1];
    scan[t] = s2;
    __syncthreads();
    for (int off = 1; off < 1024; off <<= 1) {
        unsigned v = (t + off < 1024) ? scan[t + off] : 0u;
        __syncthreads();
        scan[t] += v;
        __syncthreads();
    }
    unsigned c0 = scan[t];
    unsigned c1 = c0 - hist[2 * t];
    unsigned c2 = (t < 1023) ? scan[t + 1] : 0u;
    if (c0 >= (unsigned)M_CAND && c1 < (unsigned)M_CAND) { sh_bin1 = 2 * t;     sh_above1 = (int)c1; }
    if (c1 >= (unsigned)M_CAND && c2 < (unsigned)M_CAND) { sh_bin1 = 2 * t + 1; sh_above1 = (int)c2; }
    __syncthreads();
    int bin1 = sh_bin1, above1 = sh_above1;
    if (t < 256) hist[t] = 0;
    __syncthreads();
    for (int i = t; i < H_N; i += 1024) {
        unsigned u = orderf(row[i]);
        if ((int)(u >> 21) == bin1) atomicAdd(&hist[(u >> 13) & 0xFFu], 1u);
    }
    __syncthreads();
    if (t == 0) {
        int need = M_CAND - above1;
        unsigned acc = 0; int bin2 = 0, above2 = 0;
        for (int j = 255; j >= 0; j--) {
            unsigned nacc = acc + hist[j];
            if (acc < (unsigned)need && nacc >= (unsigned)need) { bin2 = j; above2 = (int)acc; break; }
            acc = nacc;
        }
        sh_bin2 = bin2; sh_aboveT = above1 + above2;
    }
    __syncthreads();
    unsigned pref = ((unsigned)bin1 << 8) | (unsigned)sh_bin2;
    int aboveT = sh_aboveT;
    for (int i = t; i < H_N; i += 1024) {
        unsigned u = orderf(row[i]);
        if ((u >> 13) == pref) {
            int p = atomicAdd(&ncand, 1);
            if (p < 512) { cand_u[p] = u; cand_i[p] = i; }
        }
    }
    __syncthreads();
    if (t == 0) {
        int c = ncand < 512 ? ncand : 512;
        int need = M_CAND - aboveT;
        unsigned ut = 0; int eqlim = 0x7fffffff;
        for (int i = 0; i < c; i++) {
            unsigned u = cand_u[i];
            int gt = 0, eqc = 0;
            for (int j = 0; j < c; j++) { gt += (cand_u[j] > u); eqc += (cand_u[j] == u); }
            if (gt < need && gt + eqc >= need) {
                ut = u;
                int need_eq = need - gt;
                int lim = -1;
                for (int r = 0; r < need_eq; r++) {
                    int best = 0x7fffffff;
                    for (int j = 0; j < c; j++)
                        if (cand_u[j] == u && cand_i[j] > lim && cand_i[j] < best) best = cand_i[j];
                    lim = best;
                }
                eqlim = lim;
                break;
            }
        }
        sh_uthr = ut; sh_eqlim = eqlim;
    }
    __syncthreads();
    unsigned ut = sh_uthr; int lim = sh_eqlim;
    for (int i = t; i < H_N; i += 1024) {
        unsigned u = orderf(row[i]);
        if (u > ut || (u == ut && i <= lim)) {
            int p = atomicAdd(&sh_pos, 1);
            if (p < M_CAND) cand_idx[(size_t)b * M_CAND + p] = i;
        }
    }
    __syncthreads();
    for (int p = sh_pos + t; p < M_CAND; p += 1024)
        cand_idx[(size_t)b * M_CAND + p] = -(p + 1);
}

// ---------------- f64 refine: exact latents for candidates, true top-256 ----------------
__global__ __launch_bounds__(256) void refine_kernel(const float* __restrict__ x,
        const float* __restrict__ Wenc, const double* __restrict__ invn_d,
        const int* __restrict__ cand, int* __restrict__ sel_idx, float* __restrict__ sel_val) {
    int b = blockIdx.x, t = threadIdx.x;
    int lane = t & 63, w = t >> 6;
    __shared__ double xs[D_N];
    __shared__ double vals[M_CAND];
    __shared__ int idxs[M_CAND];
    __shared__ double red[8];
    __shared__ double smu, sinv;

    const float4* row4 = (const float4*)(x + (size_t)b * D_N);
    float4 v = row4[t];
    double s  = (double)v.x + (double)v.y + (double)v.z + (double)v.w;
    double ss = (double)v.x*v.x + (double)v.y*v.y + (double)v.z*v.z + (double)v.w*v.w;
    #pragma unroll
    for (int off = 32; off > 0; off >>= 1) {
        s  += __shfl_down(s, off);
        ss += __shfl_down(ss, off);
    }
    if ((t & 63) == 0) { red[w] = s; red[4 + w] = ss; }
    __syncthreads();
    if (t == 0) {
        double S  = red[0] + red[1] + red[2] + red[3];
        double SS = red[4] + red[5] + red[6] + red[7];
        double mu = S / (double)D_N;
        double var = (SS - S * S / (double)D_N) / (double)(D_N - 1);
        double sd = sqrt(var > 0.0 ? var : 0.0);
        smu = mu; sinv = 1.0 / (sd + 1e-5);
    }
    __syncthreads();
    double mu = smu, inv = sinv;
    xs[4*t + 0] = ((double)v.x - mu) * inv;
    xs[4*t + 1] = ((double)v.y - mu) * inv;
    xs[4*t + 2] = ((double)v.z - mu) * inv;
    xs[4*t + 3] = ((double)v.w - mu) * inv;
    __syncthreads();

    for (int c = w; c < M_CAND; c += 4) {
        int h = cand[(size_t)b * M_CAND + c];
        if ((unsigned)h < (unsigned)H_N) {
            const float* wr = Wenc + (size_t)h * D_N;
            double acc = 0.0;
            for (int d = lane; d < D_N; d += 64) acc += xs[d] * (double)wr[d];
            #pragma unroll
            for (int off = 32; off > 0; off >>= 1) acc += __shfl_down(acc, off);
            if (lane == 0) { vals[c] = acc * invn_d[h]; idxs[c] = h; }
        } else {
            if (lane == 0) { vals[c] = -1e300 + (double)h; idxs[c] = h; }
        }
    }
    __syncthreads();
    for (int c = t; c < M_CAND; c += 256) {
        double vv = vals[c]; int id = idxs[c];
        int r = 0;
        for (int j = 0; j < M_CAND; j++) {
            double vj = vals[j];
            r += (vj > vv) || (vj == vv && idxs[j] < id);
        }
        if (r < K_SEL) {
            sel_idx[(size_t)b * K_SEL + r] = id;
            sel_val[(size_t)b * K_SEL + r] = (float)vv;
        }
    }
}

// ---------------- sparse decode (bf16 Wdt) + denorm ----------------
__global__ __launch_bounds__(256) void decode_kernel(const int* __restrict__ sel_idx,
        const float* __restrict__ sel_val, const unsigned short* __restrict__ Wdt,
        const float* __restrict__ mu, const float* __restrict__ stdv,
        float* __restrict__ out) {
    int b = blockIdx.x, t = threadIdx.x;
    __shared__ int sidx[K_SEL];
    __shared__ float sval[K_SEL];
    sidx[t] = sel_idx[(size_t)b * K_SEL + t];
    sval[t] = sel_val[(size_t)b * K_SEL + t];
    __syncthreads();
    float4 acc = {0.f, 0.f, 0.f, 0.f};
    for (int k = 0; k < K_SEL; k++) {
        int h = sidx[k];
        if ((unsigned)h < (unsigned)H_N) {
            ushort4 w = *(const ushort4*)(Wdt + (size_t)h * D_N + t * 4);
            float vv = sval[k];
            acc.x += vv * bf2f(w.x); acc.y += vv * bf2f(w.y);
            acc.z += vv * bf2f(w.z); acc.w += vv * bf2f(w.w);
        }
    }
    float m = mu[b], sd = stdv[b];
    float4 o;
    o.x = acc.x * sd + m; o.y = acc.y * sd + m;
    o.z = acc.z * sd + m; o.w = acc.w * sd + m;
    ((float4*)(out + (size_t)b * D_N))[t] = o;
}

extern "C" void kernel_launch(void* const* d_in, const int* in_sizes, int n_in,
                              void* d_out, int out_size, void* d_ws, size_t ws_size,
                              hipStream_t stream) {
    const float* txt  = (const float*)d_in[0];
    const float* Wenc = (const float*)d_in[1];
    const float* Wdec = (const float*)d_in[2];
    float* recons = (float*)d_out;
    float* lat    = (float*)d_out + (size_t)B_N * D_N;

    char* p = (char*)d_ws;
    unsigned short* xnbf = (unsigned short*)p;  p += (size_t)B_N * D_N * 2;   // 4 MB
    unsigned short* Wbf  = (unsigned short*)p;  p += (size_t)H_N * D_N * 2;   // 64 MB
    unsigned short* Wdt  = (unsigned short*)p;  p += (size_t)H_N * D_N * 2;   // 64 MB
    double* invn_d = (double*)p;  p += (size_t)H_N * 8;                       // 256 KB
    float* muv = (float*)p;       p += (size_t)B_N * 4;
    float* stdv = (float*)p;      p += (size_t)B_N * 4;
    int* candidx = (int*)p;       p += (size_t)B_N * M_CAND * 4;              // 2.6 MB
    int* selidx = (int*)p;        p += (size_t)B_N * K_SEL * 4;
    float* selval = (float*)p;    p += (size_t)B_N * K_SEL * 4;

    ln_kernel<<<B_N, 256, 0, stream>>>(txt, xnbf, muv, stdv);
    wconv_kernel<<<H_N, 256, 0, stream>>>(Wenc, Wbf, invn_d);
    enc_gemm_bf16<<<dim3(H_N / 128, B_N / 128), 256, 0, stream>>>(xnbf, Wbf, lat);
    transpose_kernel<<<dim3(H_N / 32, D_N / 32), dim3(32, 8), 0, stream>>>(Wdec, Wdt);
    candk_kernel<<<B_N, 1024, 0, stream>>>(lat, candidx);
    refine_kernel<<<B_N, 256, 0, stream>>>(txt, Wenc, invn_d, candidx, selidx, selval);
    decode_kernel<<<B_N, 256, 0, stream>>>(selidx, selval, Wdt, muv, stdv, recons);
}

// Round 4
// 1023.091 us; speedup vs baseline: 2.6716x; 1.2999x over previous
//
#include <hip/hip_runtime.h>
#include <math.h>

#define B_N 2048
#define D_N 1024
#define H_N 32768
#define K_SEL 256
#define M_CAND 320
#define EPS_V 1e-5f

typedef __bf16 bf16x8 __attribute__((ext_vector_type(8)));
typedef float f32x4 __attribute__((ext_vector_type(4)));

__device__ __forceinline__ unsigned orderf(float x) {
    unsigned f = __float_as_uint(x);
    return (f & 0x80000000u) ? ~f : (f | 0x80000000u);
}

__device__ __forceinline__ unsigned short f2bf(float f) {
    unsigned u = __float_as_uint(f);
    unsigned r = u + 0x7FFFu + ((u >> 16) & 1u);   // RNE
    return (unsigned short)(r >> 16);
}

__device__ __forceinline__ float bf2f(unsigned short b) {
    return __uint_as_float((unsigned)b << 16);
}

// ---------------- LN preprocess -> bf16 xn + mu/std ----------------
__global__ __launch_bounds__(256) void ln_kernel(const float* __restrict__ x,
        unsigned short* __restrict__ xnbf, float* __restrict__ mu_out, float* __restrict__ std_out) {
    int b = blockIdx.x, t = threadIdx.x;
    const float4* row = (const float4*)(x + (size_t)b * D_N);
    float4 v = row[t];
    float s  = v.x + v.y + v.z + v.w;
    float ss = v.x*v.x + v.y*v.y + v.z*v.z + v.w*v.w;
    #pragma unroll
    for (int off = 32; off > 0; off >>= 1) {
        s  += __shfl_down(s, off);
        ss += __shfl_down(ss, off);
    }
    __shared__ float ls[4], lss[4];
    __shared__ float smu, sinv;
    int w = t >> 6;
    if ((t & 63) == 0) { ls[w] = s; lss[w] = ss; }
    __syncthreads();
    if (t == 0) {
        float S  = ls[0] + ls[1] + ls[2] + ls[3];
        float SS = lss[0] + lss[1] + lss[2] + lss[3];
        float mu = S / (float)D_N;
        float var = (SS - S * S / (float)D_N) / (float)(D_N - 1);
        float sd = sqrtf(fmaxf(var, 0.f));
        smu = mu; sinv = 1.f / (sd + EPS_V);
        mu_out[b] = mu; std_out[b] = sd;
    }
    __syncthreads();
    float mu = smu, inv = sinv;
    ushort4 o;
    o.x = f2bf((v.x - mu) * inv); o.y = f2bf((v.y - mu) * inv);
    o.z = f2bf((v.z - mu) * inv); o.w = f2bf((v.w - mu) * inv);
    *(ushort4*)(xnbf + (size_t)b * D_N + t * 4) = o;
}

// ---------------- W_enc: f64 row norm, bf16 normalized rows ----------------
__global__ __launch_bounds__(256) void wconv_kernel(const float* __restrict__ W,
        unsigned short* __restrict__ Wbf, double* __restrict__ inv_norm_d) {
    int h = blockIdx.x, t = threadIdx.x;
    const float4* row = (const float4*)(W + (size_t)h * D_N);
    float4 v = row[t];
    double ss = (double)v.x*v.x + (double)v.y*v.y + (double)v.z*v.z + (double)v.w*v.w;
    #pragma unroll
    for (int off = 32; off > 0; off >>= 1) ss += __shfl_down(ss, off);
    __shared__ double lss[4];
    __shared__ float sinv;
    int w = t >> 6;
    if ((t & 63) == 0) lss[w] = ss;
    __syncthreads();
    if (t == 0) {
        double SS = lss[0] + lss[1] + lss[2] + lss[3];
        double n = sqrt(SS);
        if (n < 1e-12) n = 1e-12;
        inv_norm_d[h] = 1.0 / n;
        sinv = (float)(1.0 / n);
    }
    __syncthreads();
    float invf = sinv;
    ushort4 o;
    o.x = f2bf(v.x * invf); o.y = f2bf(v.y * invf);
    o.z = f2bf(v.z * invf); o.w = f2bf(v.w * invf);
    *(ushort4*)(Wbf + (size_t)h * D_N + t * 4) = o;
}

// ---------------- bf16 MFMA GEMM: lat[b,h] = dot(xnbf[b,:], Wbf[h,:]) ----------------
__global__ __launch_bounds__(256) void enc_gemm_bf16(const unsigned short* __restrict__ A,
        const unsigned short* __restrict__ Bm, float* __restrict__ C) {
    __shared__ alignas(16) unsigned short As[128 * 32];
    __shared__ alignas(16) unsigned short Bs[128 * 32];
    int t = threadIdx.x;
    int wid = t >> 6, lane = t & 63;
    int bn = blockIdx.x, bm = blockIdx.y;
    int wr = wid >> 1, wc = wid & 1;
    int fr = lane & 15, kq = lane >> 4;

    size_t arow0 = (size_t)bm * 128;
    size_t brow0 = (size_t)bn * 128;

    const unsigned short* gA0 = A  + (arow0 + (t >> 2)) * D_N + (t & 3) * 8;
    const unsigned short* gA1 = A  + (arow0 + 64 + (t >> 2)) * D_N + (t & 3) * 8;
    const unsigned short* gB0 = Bm + (brow0 + (t >> 2)) * D_N + (t & 3) * 8;
    const unsigned short* gB1 = Bm + (brow0 + 64 + (t >> 2)) * D_N + (t & 3) * 8;

    f32x4 acc[4][4];
    #pragma unroll
    for (int i = 0; i < 4; i++)
        #pragma unroll
        for (int j = 0; j < 4; j++)
            acc[i][j] = (f32x4){0.f, 0.f, 0.f, 0.f};

    uint4 ra0 = *(const uint4*)(gA0);
    uint4 ra1 = *(const uint4*)(gA1);
    uint4 rb0 = *(const uint4*)(gB0);
    uint4 rb1 = *(const uint4*)(gB1);

    for (int ks = 0; ks < D_N / 32; ks++) {
        __syncthreads();
        *(uint4*)&As[t * 8]        = ra0;
        *(uint4*)&As[2048 + t * 8] = ra1;
        *(uint4*)&Bs[t * 8]        = rb0;
        *(uint4*)&Bs[2048 + t * 8] = rb1;
        __syncthreads();
        if (ks + 1 < D_N / 32) {
            int k0 = (ks + 1) * 32;
            ra0 = *(const uint4*)(gA0 + k0);
            ra1 = *(const uint4*)(gA1 + k0);
            rb0 = *(const uint4*)(gB0 + k0);
            rb1 = *(const uint4*)(gB1 + k0);
        }
        bf16x8 af[4], bfr[4];
        #pragma unroll
        for (int i = 0; i < 4; i++) {
            int ra = wr * 64 + i * 16 + fr;
            af[i] = *(const bf16x8*)&As[ra * 32 + kq * 8];
            int rb = wc * 64 + i * 16 + fr;
            bfr[i] = *(const bf16x8*)&Bs[rb * 32 + kq * 8];
        }
        #pragma unroll
        for (int i = 0; i < 4; i++)
            #pragma unroll
            for (int j = 0; j < 4; j++)
                acc[i][j] = __builtin_amdgcn_mfma_f32_16x16x32_bf16(af[i], bfr[j], acc[i][j], 0, 0, 0);
    }

    #pragma unroll
    for (int i = 0; i < 4; i++) {
        int r0 = bm * 128 + wr * 64 + i * 16 + kq * 4;
        #pragma unroll
        for (int j = 0; j < 4; j++) {
            int c = bn * 128 + wc * 64 + j * 16 + fr;
            #pragma unroll
            for (int r = 0; r < 4; r++)
                C[(size_t)(r0 + r) * H_N + c] = acc[i][j][r];
        }
    }
}

// ---------------- W_dec transpose [D][H] -> bf16 [H][D] ----------------
__global__ void transpose_kernel(const float* __restrict__ in, unsigned short* __restrict__ out) {
    __shared__ float tile[32][33];
    int x  = blockIdx.x * 32 + threadIdx.x;     // h
    int y0 = blockIdx.y * 32;                   // d
    #pragma unroll
    for (int j = threadIdx.y; j < 32; j += 8)
        tile[j][threadIdx.x] = in[(size_t)(y0 + j) * H_N + x];
    __syncthreads();
    int xo  = blockIdx.y * 32 + threadIdx.x;    // d
    int yo0 = blockIdx.x * 32;                  // h
    #pragma unroll
    for (int j = threadIdx.y; j < 32; j += 8)
        out[(size_t)(yo0 + j) * D_N + xo] = f2bf(tile[threadIdx.x][j]);
}

// ---------------- per-row top-M candidate extraction (register-staged row) ----------------
__global__ __launch_bounds__(1024) void candk_kernel(const float* __restrict__ lat,
        int* __restrict__ cand_idx) {
    int b = blockIdx.x, t = threadIdx.x;
    const float* row = lat + (size_t)b * H_N;
    __shared__ unsigned hist[2048];
    __shared__ unsigned scan[1024];
    __shared__ int sh_bin1, sh_above1, sh_bin2, sh_aboveT;
    __shared__ unsigned cand_u[512];
    __shared__ int cand_i[512];
    __shared__ int ncand;
    __shared__ unsigned sh_uthr;
    __shared__ int sh_eqlim, sh_pos;

    // stage the whole row in registers: uv[j] corresponds to index t + (j<<10)
    unsigned uv[32];
    #pragma unroll
    for (int j = 0; j < 32; j++)
        uv[j] = orderf(row[t + (j << 10)]);

    hist[t] = 0; hist[t + 1024] = 0;
    if (t == 0) { ncand = 0; sh_pos = 0; }
    __syncthreads();
    #pragma unroll
    for (int j = 0; j < 32; j++)
        atomicAdd(&hist[uv[j] >> 21], 1u);
    __syncthreads();
    unsigned s2 = hist[2 * t] + hist[2 * t + 1];
    scan[t] = s2;
    __syncthreads();
    for (int off = 1; off < 1024; off <<= 1) {
        unsigned v = (t + off < 1024) ? scan[t + off] : 0u;
        __syncthreads();
        scan[t] += v;
        __syncthreads();
    }
    unsigned c0 = scan[t];
    unsigned c1 = c0 - hist[2 * t];
    unsigned c2 = (t < 1023) ? scan[t + 1] : 0u;
    if (c0 >= (unsigned)M_CAND && c1 < (unsigned)M_CAND) { sh_bin1 = 2 * t;     sh_above1 = (int)c1; }
    if (c1 >= (unsigned)M_CAND && c2 < (unsigned)M_CAND) { sh_bin1 = 2 * t + 1; sh_above1 = (int)c2; }
    __syncthreads();
    int bin1 = sh_bin1, above1 = sh_above1;
    if (t < 256) hist[t] = 0;
    __syncthreads();
    #pragma unroll
    for (int j = 0; j < 32; j++)
        if ((int)(uv[j] >> 21) == bin1) atomicAdd(&hist[(uv[j] >> 13) & 0xFFu], 1u);
    __syncthreads();
    if (t == 0) {
        int need = M_CAND - above1;
        unsigned acc = 0; int bin2 = 0, above2 = 0;
        for (int j = 255; j >= 0; j--) {
            unsigned nacc = acc + hist[j];
            if (acc < (unsigned)need && nacc >= (unsigned)need) { bin2 = j; above2 = (int)acc; break; }
            acc = nacc;
        }
        sh_bin2 = bin2; sh_aboveT = above1 + above2;
    }
    __syncthreads();
    unsigned pref = ((unsigned)bin1 << 8) | (unsigned)sh_bin2;
    int aboveT = sh_aboveT;
    #pragma unroll
    for (int j = 0; j < 32; j++) {
        if ((uv[j] >> 13) == pref) {
            int p = atomicAdd(&ncand, 1);
            if (p < 512) { cand_u[p] = uv[j]; cand_i[p] = t + (j << 10); }
        }
    }
    __syncthreads();
    if (t == 0) {
        int c = ncand < 512 ? ncand : 512;
        int need = M_CAND - aboveT;
        unsigned ut = 0; int eqlim = 0x7fffffff;
        for (int i = 0; i < c; i++) {
            unsigned u = cand_u[i];
            int gt = 0, eqc = 0;
            for (int j = 0; j < c; j++) { gt += (cand_u[j] > u); eqc += (cand_u[j] == u); }
            if (gt < need && gt + eqc >= need) {
                ut = u;
                int need_eq = need - gt;
                int lim = -1;
                for (int r = 0; r < need_eq; r++) {
                    int best = 0x7fffffff;
                    for (int j = 0; j < c; j++)
                        if (cand_u[j] == u && cand_i[j] > lim && cand_i[j] < best) best = cand_i[j];
                    lim = best;
                }
                eqlim = lim;
                break;
            }
        }
        sh_uthr = ut; sh_eqlim = eqlim;
    }
    __syncthreads();
    unsigned ut = sh_uthr; int lim = sh_eqlim;
    #pragma unroll
    for (int j = 0; j < 32; j++) {
        unsigned u = uv[j];
        int i = t + (j << 10);
        if (u > ut || (u == ut && i <= lim)) {
            int p = atomicAdd(&sh_pos, 1);
            if (p < M_CAND) cand_idx[(size_t)b * M_CAND + p] = i;
        }
    }
    __syncthreads();
    for (int p = sh_pos + t; p < M_CAND; p += 1024)
        cand_idx[(size_t)b * M_CAND + p] = -(p + 1);
}

// ---------------- f64 refine: xs in registers, vectorized W loads ----------------
__global__ __launch_bounds__(256) void refine_kernel(const float* __restrict__ x,
        const float* __restrict__ Wenc, const double* __restrict__ invn_d,
        const int* __restrict__ cand, int* __restrict__ sel_idx, float* __restrict__ sel_val) {
    int b = blockIdx.x, t = threadIdx.x;
    int lane = t & 63, w = t >> 6;
    __shared__ double xs[D_N];
    __shared__ double vals[M_CAND];
    __shared__ int idxs[M_CAND];
    __shared__ double red[8];
    __shared__ double smu, sinv;

    const float4* row4 = (const float4*)(x + (size_t)b * D_N);
    float4 v = row4[t];
    double s  = (double)v.x + (double)v.y + (double)v.z + (double)v.w;
    double ss = (double)v.x*v.x + (double)v.y*v.y + (double)v.z*v.z + (double)v.w*v.w;
    #pragma unroll
    for (int off = 32; off > 0; off >>= 1) {
        s  += __shfl_down(s, off);
        ss += __shfl_down(ss, off);
    }
    if ((t & 63) == 0) { red[w] = s; red[4 + w] = ss; }
    __syncthreads();
    if (t == 0) {
        double S  = red[0] + red[1] + red[2] + red[3];
        double SS = red[4] + red[5] + red[6] + red[7];
        double mu = S / (double)D_N;
        double var = (SS - S * S / (double)D_N) / (double)(D_N - 1);
        double sd = sqrt(var > 0.0 ? var : 0.0);
        smu = mu; sinv = 1.0 / (sd + 1e-5);
    }
    __syncthreads();
    double mu = smu, inv = sinv;
    xs[4*t + 0] = ((double)v.x - mu) * inv;
    xs[4*t + 1] = ((double)v.y - mu) * inv;
    xs[4*t + 2] = ((double)v.z - mu) * inv;
    xs[4*t + 3] = ((double)v.w - mu) * inv;
    __syncthreads();

    // each lane caches its 16 xs values: dims 4*lane + 256*r + j  (r=0..3, j=0..3)
    double xr[16];
    #pragma unroll
    for (int r = 0; r < 4; r++)
        #pragma unroll
        for (int j = 0; j < 4; j++)
            xr[r * 4 + j] = xs[4 * lane + 256 * r + j];

    const float4* W4 = (const float4*)Wenc;
    for (int c = w; c < M_CAND; c += 4) {
        int h = cand[(size_t)b * M_CAND + c];
        if ((unsigned)h < (unsigned)H_N) {
            const float4* wr = W4 + (size_t)h * 256;
            float4 w0 = wr[lane];
            float4 w1 = wr[lane + 64];
            float4 w2 = wr[lane + 128];
            float4 w3 = wr[lane + 192];
            double a0 = (double)w0.x*xr[0]  + (double)w0.y*xr[1]  + (double)w0.z*xr[2]  + (double)w0.w*xr[3];
            double a1 = (double)w1.x*xr[4]  + (double)w1.y*xr[5]  + (double)w1.z*xr[6]  + (double)w1.w*xr[7];
            double a2 = (double)w2.x*xr[8]  + (double)w2.y*xr[9]  + (double)w2.z*xr[10] + (double)w2.w*xr[11];
            double a3 = (double)w3.x*xr[12] + (double)w3.y*xr[13] + (double)w3.z*xr[14] + (double)w3.w*xr[15];
            double p = (a0 + a1) + (a2 + a3);
            #pragma unroll
            for (int off = 32; off > 0; off >>= 1) p += __shfl_down(p, off);
            if (lane == 0) { vals[c] = p * invn_d[h]; idxs[c] = h; }
        } else {
            if (lane == 0) { vals[c] = -1e300 + (double)h; idxs[c] = h; }
        }
    }
    __syncthreads();
    for (int c = t; c < M_CAND; c += 256) {
        double vv = vals[c]; int id = idxs[c];
        int r = 0;
        for (int j = 0; j < M_CAND; j++) {
            double vj = vals[j];
            r += (vj > vv) || (vj == vv && idxs[j] < id);
        }
        if (r < K_SEL) {
            sel_idx[(size_t)b * K_SEL + r] = id;
            sel_val[(size_t)b * K_SEL + r] = (float)vv;
        }
    }
}

// ---------------- sparse decode (bf16 Wdt) + denorm ----------------
__global__ __launch_bounds__(256) void decode_kernel(const int* __restrict__ sel_idx,
        const float* __restrict__ sel_val, const unsigned short* __restrict__ Wdt,
        const float* __restrict__ mu, const float* __restrict__ stdv,
        float* __restrict__ out) {
    int b = blockIdx.x, t = threadIdx.x;
    __shared__ int sidx[K_SEL];
    __shared__ float sval[K_SEL];
    sidx[t] = sel_idx[(size_t)b * K_SEL + t];
    sval[t] = sel_val[(size_t)b * K_SEL + t];
    __syncthreads();
    float4 acc = {0.f, 0.f, 0.f, 0.f};
    for (int k = 0; k < K_SEL; k++) {
        int h = sidx[k];
        if ((unsigned)h < (unsigned)H_N) {
            ushort4 w = *(const ushort4*)(Wdt + (size_t)h * D_N + t * 4);
            float vv = sval[k];
            acc.x += vv * bf2f(w.x); acc.y += vv * bf2f(w.y);
            acc.z += vv * bf2f(w.z); acc.w += vv * bf2f(w.w);
        }
    }
    float m = mu[b], sd = stdv[b];
    float4 o;
    o.x = acc.x * sd + m; o.y = acc.y * sd + m;
    o.z = acc.z * sd + m; o.w = acc.w * sd + m;
    ((float4*)(out + (size_t)b * D_N))[t] = o;
}

extern "C" void kernel_launch(void* const* d_in, const int* in_sizes, int n_in,
                              void* d_out, int out_size, void* d_ws, size_t ws_size,
                              hipStream_t stream) {
    const float* txt  = (const float*)d_in[0];
    const float* Wenc = (const float*)d_in[1];
    const float* Wdec = (const float*)d_in[2];
    float* recons = (float*)d_out;
    float* lat    = (float*)d_out + (size_t)B_N * D_N;

    char* p = (char*)d_ws;
    unsigned short* xnbf = (unsigned short*)p;  p += (size_t)B_N * D_N * 2;   // 4 MB
    unsigned short* Wbf  = (unsigned short*)p;  p += (size_t)H_N * D_N * 2;   // 64 MB
    unsigned short* Wdt  = (unsigned short*)p;  p += (size_t)H_N * D_N * 2;   // 64 MB
    double* invn_d = (double*)p;  p += (size_t)H_N * 8;                       // 256 KB
    float* muv = (float*)p;       p += (size_t)B_N * 4;
    float* stdv = (float*)p;      p += (size_t)B_N * 4;
    int* candidx = (int*)p;       p += (size_t)B_N * M_CAND * 4;              // 2.6 MB
    int* selidx = (int*)p;        p += (size_t)B_N * K_SEL * 4;
    float* selval = (float*)p;    p += (size_t)B_N * K_SEL * 4;

    ln_kernel<<<B_N, 256, 0, stream>>>(txt, xnbf, muv, stdv);
    wconv_kernel<<<H_N, 256, 0, stream>>>(Wenc, Wbf, invn_d);
    enc_gemm_bf16<<<dim3(H_N / 128, B_N / 128), 256, 0, stream>>>(xnbf, Wbf, lat);
    transpose_kernel<<<dim3(H_N / 32, D_N / 32), dim3(32, 8), 0, stream>>>(Wdec, Wdt);
    candk_kernel<<<B_N, 1024, 0, stream>>>(lat, candidx);
    refine_kernel<<<B_N, 256, 0, stream>>>(txt, Wenc, invn_d, candidx, selidx, selval);
    decode_kernel<<<B_N, 256, 0, stream>>>(selidx, selval, Wdt, muv, stdv, recons);
}